// Round 1
// baseline (546.948 us; speedup 1.0000x reference)
//
#include <hip/hip_runtime.h>

#define NEG_SLOPE 0.01f

static __device__ __forceinline__ float lrelu(float v) {
    return v >= 0.0f ? v : NEG_SLOPE * v;
}

// ---------------- init: zero counters + pooled ----------------
__global__ void k_init(int* cnt, int* fill, float* pooled, int n, int npool) {
    int i = blockIdx.x * blockDim.x + threadIdx.x;
    if (i < n) { cnt[i] = 0; fill[i] = 0; }
    if (i < npool) pooled[i] = 0.0f;
}

// ---------------- degree histogram over dst ----------------
__global__ void k_count(const int* __restrict__ edge, int E, int* cnt) {
    int e = blockIdx.x * blockDim.x + threadIdx.x;
    if (e < E) atomicAdd(&cnt[edge[E + e]], 1);
}

// ---------------- dinv = (deg+1)^-0.5 (self loop included) ----------------
__global__ void k_dinv(const int* __restrict__ cnt, float* dinv, int n) {
    int i = blockIdx.x * blockDim.x + threadIdx.x;
    if (i < n) dinv[i] = rsqrtf((float)(cnt[i] + 1));
}

// ---------------- 3-kernel exclusive scan (N = 131072 = 512*256) ----------------
__global__ void k_scanA(const int* __restrict__ cnt, int* rowoff, int* partial, int n) {
    __shared__ int s[256];
    int tid = threadIdx.x;
    int gid = blockIdx.x * 256 + tid;
    int v = (gid < n) ? cnt[gid] : 0;
    s[tid] = v;
    __syncthreads();
    for (int off = 1; off < 256; off <<= 1) {
        int t = (tid >= off) ? s[tid - off] : 0;
        __syncthreads();
        s[tid] += t;
        __syncthreads();
    }
    if (gid < n) rowoff[gid] = s[tid] - v;   // exclusive within chunk
    if (tid == 255) partial[blockIdx.x] = s[tid];
}

__global__ void k_scanB(int* partial, int P) {
    __shared__ int s[1024];
    int tid = threadIdx.x;
    int v = (tid < P) ? partial[tid] : 0;
    s[tid] = v;
    __syncthreads();
    for (int off = 1; off < P; off <<= 1) {
        int t = (tid >= off) ? s[tid - off] : 0;
        __syncthreads();
        s[tid] += t;
        __syncthreads();
    }
    if (tid < P) partial[tid] = s[tid] - v;  // exclusive over partials
}

__global__ void k_scanC(int* rowoff, const int* __restrict__ partial, int n, int E) {
    int gid = blockIdx.x * blockDim.x + threadIdx.x;
    if (gid < n) rowoff[gid] += partial[gid >> 8];
    if (gid == 0) rowoff[n] = E;
}

// ---------------- CSR fill: colsrc sorted by dst ----------------
__global__ void k_fill(const int* __restrict__ edge, int E,
                       const int* __restrict__ rowoff, int* fill, int* colsrc) {
    int e = blockIdx.x * blockDim.x + threadIdx.x;
    if (e < E) {
        int dst = edge[E + e];
        int pos = rowoff[dst] + atomicAdd(&fill[dst], 1);
        colsrc[pos] = edge[e];
    }
}

// ---------------- h = x @ W  (fp32, 64-row x 128-col tiles, BK=32) ----------------
#define BM 64
#define BK 32
__global__ __launch_bounds__(256) void k_gemm(const float* __restrict__ x,
                                              const float* __restrict__ W,
                                              float* __restrict__ h) {
    __shared__ float Xs[BM][BK + 4];   // row stride 36 words (144B, 16B aligned)
    __shared__ float Ws[BK][128];
    int tid = threadIdx.x;
    int tx = tid & 15;          // 16 col groups: cols tx*4..tx*4+3 and +64
    int ty = tid >> 4;          // 16 row groups: rows ty*4..ty*4+3
    long r0 = (long)blockIdx.x * BM;

    float acc[4][8];
#pragma unroll
    for (int j = 0; j < 4; ++j)
#pragma unroll
        for (int c = 0; c < 8; ++c) acc[j][c] = 0.0f;

    for (int k0 = 0; k0 < 128; k0 += BK) {
        // stage X tile: 64 rows x 32 k  (512 float4, 2 per thread)
#pragma unroll
        for (int it = 0; it < 2; ++it) {
            int i = tid + it * 256;
            int row = i >> 3;
            int kq = i & 7;
            float4 v = *(const float4*)&x[(r0 + row) * 128 + k0 + kq * 4];
            *(float4*)&Xs[row][kq * 4] = v;
        }
        // stage W tile: 32 k x 128 cols (1024 float4, 4 per thread)
#pragma unroll
        for (int it = 0; it < 4; ++it) {
            int i = tid + it * 256;
            int kk = i >> 5;
            int cq = i & 31;
            *(float4*)&Ws[kk][cq * 4] = *(const float4*)&W[(k0 + kk) * 128 + cq * 4];
        }
        __syncthreads();

#pragma unroll
        for (int k = 0; k < BK; k += 4) {
            float4 xf[4];
#pragma unroll
            for (int j = 0; j < 4; ++j) xf[j] = *(const float4*)&Xs[ty * 4 + j][k];
#pragma unroll
            for (int kk = 0; kk < 4; ++kk) {
                float4 wa = *(const float4*)&Ws[k + kk][tx * 4];
                float4 wb = *(const float4*)&Ws[k + kk][tx * 4 + 64];
#pragma unroll
                for (int j = 0; j < 4; ++j) {
                    float xs = ((const float*)&xf[j])[kk];
                    acc[j][0] += xs * wa.x;
                    acc[j][1] += xs * wa.y;
                    acc[j][2] += xs * wa.z;
                    acc[j][3] += xs * wa.w;
                    acc[j][4] += xs * wb.x;
                    acc[j][5] += xs * wb.y;
                    acc[j][6] += xs * wb.z;
                    acc[j][7] += xs * wb.w;
                }
            }
        }
        __syncthreads();
    }
#pragma unroll
    for (int j = 0; j < 4; ++j) {
        long r = r0 + ty * 4 + j;
        float4 va = {acc[j][0], acc[j][1], acc[j][2], acc[j][3]};
        float4 vb = {acc[j][4], acc[j][5], acc[j][6], acc[j][7]};
        *(float4*)&h[r * 128 + tx * 4] = va;
        *(float4*)&h[r * 128 + tx * 4 + 64] = vb;
    }
}

// ---------------- aggregation: one wave per node, atomic into pooled ----------------
__global__ __launch_bounds__(256) void k_aggr(const float* __restrict__ h,
                                              const int* __restrict__ colsrc,
                                              const int* __restrict__ rowoff,
                                              const float* __restrict__ dinv,
                                              const float* __restrict__ bias,
                                              float* pooled, int n) {
    int wave = threadIdx.x >> 6;
    int lane = threadIdx.x & 63;
    int v = blockIdx.x * 4 + wave;
    if (v >= n) return;

    float dv = dinv[v];
    float2 acc = ((const float2*)&h[(size_t)v * 128])[lane];
    float dv2 = dv * dv;
    acc.x *= dv2;
    acc.y *= dv2;

    int s = rowoff[v];
    int e = rowoff[v + 1];
    for (int i = s; i < e; ++i) {
        int src = colsrc[i];
        float nrm = dinv[src] * dv;
        float2 hs = ((const float2*)&h[(size_t)src * 128])[lane];
        acc.x += hs.x * nrm;
        acc.y += hs.y * nrm;
    }
    float2 bv = ((const float2*)bias)[lane];
    acc.x = lrelu(acc.x + bv.x);
    acc.y = lrelu(acc.y + bv.y);

    const float scale = 1.0f / 128.0f;
    float* p = &pooled[(size_t)(v >> 7) * 128 + lane * 2];
    atomicAdd(p, acc.x * scale);
    atomicAdd(p + 1, acc.y * scale);
}

// ---------------- fused MLPs: 4 graph-rows per block ----------------
#define RB 4
__global__ __launch_bounds__(256) void k_mlp(const float* __restrict__ pooled,
                                             const float* __restrict__ w1a, const float* __restrict__ b1a,
                                             const float* __restrict__ w1b, const float* __restrict__ b1b,
                                             const float* __restrict__ w2a, const float* __restrict__ b2a,
                                             const float* __restrict__ w2b, const float* __restrict__ b2b,
                                             float* __restrict__ out, int B) {
    __shared__ float row[RB][128];
    __shared__ float hid[2][RB][256];
    int tid = threadIdx.x;
    int g0 = blockIdx.x * RB;

    for (int i = tid; i < RB * 128; i += 256)
        row[i >> 7][i & 127] = pooled[(size_t)g0 * 128 + i];
    __syncthreads();

    // stage 1: hidden1 / hidden2, thread = output unit j (0..255)
    float a1[RB], a2[RB];
#pragma unroll
    for (int r = 0; r < RB; ++r) { a1[r] = 0.0f; a2[r] = 0.0f; }
    for (int k = 0; k < 128; ++k) {
        float wv1 = w1a[k * 256 + tid];
        float wv2 = w2a[k * 256 + tid];
#pragma unroll
        for (int r = 0; r < RB; ++r) {
            float xv = row[r][k];
            a1[r] += xv * wv1;
            a2[r] += xv * wv2;
        }
    }
    float bb1 = b1a[tid], bb2 = b2a[tid];
#pragma unroll
    for (int r = 0; r < RB; ++r) {
        hid[0][r][tid] = lrelu(a1[r] + bb1);
        hid[1][r][tid] = lrelu(a2[r] + bb2);
    }
    __syncthreads();

    // stage 2: threads 0..127 -> x1, threads 128..255 -> x2
    int p = tid >> 7;
    int i = tid & 127;
    const float* wb = p ? w2b : w1b;
    const float* bv = p ? b2b : b1b;
    float o[RB];
#pragma unroll
    for (int r = 0; r < RB; ++r) o[r] = 0.0f;
    for (int k = 0; k < 256; ++k) {
        float wv = wb[k * 128 + i];
#pragma unroll
        for (int r = 0; r < RB; ++r) o[r] += hid[p][r][k] * wv;
    }
    float bias = bv[i];
#pragma unroll
    for (int r = 0; r < RB; ++r)
        out[(size_t)p * B * 128 + (size_t)(g0 + r) * 128 + i] = o[r] + bias;
}

extern "C" void kernel_launch(void* const* d_in, const int* in_sizes, int n_in,
                              void* d_out, int out_size, void* d_ws, size_t ws_size,
                              hipStream_t stream) {
    const float* x    = (const float*)d_in[0];
    const int*   edge = (const int*)d_in[1];
    const float* W    = (const float*)d_in[2];
    const float* b    = (const float*)d_in[3];
    const float* w1a  = (const float*)d_in[4];
    const float* b1a  = (const float*)d_in[5];
    const float* w1b  = (const float*)d_in[6];
    const float* b1b  = (const float*)d_in[7];
    const float* w2a  = (const float*)d_in[8];
    const float* b2a  = (const float*)d_in[9];
    const float* w2b  = (const float*)d_in[10];
    const float* b2b  = (const float*)d_in[11];

    int n = in_sizes[0] / 128;      // 131072 nodes
    int E = in_sizes[1] / 2;        // 2097152 edges
    int B = n / 128;                // 1024 graphs

    // workspace layout
    char* ws = (char*)d_ws;
    size_t off = 0;
    auto alloc = [&](size_t bytes) -> void* {
        void* p = ws + off;
        off = (off + bytes + 255) & ~(size_t)255;
        return p;
    };
    float* h      = (float*)alloc((size_t)n * 128 * 4);
    int*   cnt    = (int*)alloc((size_t)n * 4);
    int*   fill   = (int*)alloc((size_t)n * 4);
    int*   rowoff = (int*)alloc((size_t)(n + 1) * 4);
    float* dinv   = (float*)alloc((size_t)n * 4);
    int*   colsrc = (int*)alloc((size_t)E * 4);
    float* pooled = (float*)alloc((size_t)B * 128 * 4);
    int*   partial= (int*)alloc(2048 * 4);
    (void)ws_size; (void)n_in; (void)out_size;

    int nblk = (n + 255) / 256;          // 512
    int eblk = (E + 255) / 256;          // 8192
    int P    = (n + 255) / 256;          // #scan partials = 512

    hipLaunchKernelGGL(k_init,  dim3(nblk), dim3(256), 0, stream, cnt, fill, pooled, n, B * 128);
    hipLaunchKernelGGL(k_count, dim3(eblk), dim3(256), 0, stream, edge, E, cnt);
    hipLaunchKernelGGL(k_dinv,  dim3(nblk), dim3(256), 0, stream, cnt, dinv, n);
    hipLaunchKernelGGL(k_scanA, dim3(nblk), dim3(256), 0, stream, cnt, rowoff, partial, n);
    hipLaunchKernelGGL(k_scanB, dim3(1),    dim3(P),   0, stream, partial, P);
    hipLaunchKernelGGL(k_scanC, dim3(nblk), dim3(256), 0, stream, rowoff, partial, n, E);
    hipLaunchKernelGGL(k_fill,  dim3(eblk), dim3(256), 0, stream, edge, E, rowoff, fill, colsrc);
    hipLaunchKernelGGL(k_gemm,  dim3(n / BM), dim3(256), 0, stream, x, W, h);
    hipLaunchKernelGGL(k_aggr,  dim3(n / 4), dim3(256), 0, stream, h, colsrc, rowoff, dinv, b, pooled, n);
    hipLaunchKernelGGL(k_mlp,   dim3(B / RB), dim3(256), 0, stream,
                       pooled, w1a, b1a, w1b, b1b, w2a, b2a, w2b, b2b, (float*)d_out, B);
}

// Round 2
// 465.653 us; speedup vs baseline: 1.1746x; 1.1746x over previous
//
#include <hip/hip_runtime.h>

#define NEG_SLOPE 0.01f

static __device__ __forceinline__ float lrelu(float v) {
    return v >= 0.0f ? v : NEG_SLOPE * v;
}

// ---------------- degree histogram over dst ----------------
__global__ void k_count(const int* __restrict__ edge, int E, int* cnt) {
    int e = blockIdx.x * blockDim.x + threadIdx.x;
    if (e < E) atomicAdd(&cnt[edge[E + e]], 1);
}

// ---------------- 3-kernel exclusive scan (N = 131072 = 512*256), fused dinv ----------------
__global__ void k_scanA(const int* __restrict__ cnt, int* rowoff, int* partial,
                        float* dinv, int n) {
    __shared__ int s[256];
    int tid = threadIdx.x;
    int gid = blockIdx.x * 256 + tid;
    int v = (gid < n) ? cnt[gid] : 0;
    if (gid < n) dinv[gid] = rsqrtf((float)(v + 1));   // self loop included
    s[tid] = v;
    __syncthreads();
    for (int off = 1; off < 256; off <<= 1) {
        int t = (tid >= off) ? s[tid - off] : 0;
        __syncthreads();
        s[tid] += t;
        __syncthreads();
    }
    if (gid < n) rowoff[gid] = s[tid] - v;   // exclusive within chunk
    if (tid == 255) partial[blockIdx.x] = s[tid];
}

__global__ void k_scanB(int* partial, int P) {
    __shared__ int s[1024];
    int tid = threadIdx.x;
    int v = (tid < P) ? partial[tid] : 0;
    s[tid] = v;
    __syncthreads();
    for (int off = 1; off < P; off <<= 1) {
        int t = (tid >= off) ? s[tid - off] : 0;
        __syncthreads();
        s[tid] += t;
        __syncthreads();
    }
    if (tid < P) partial[tid] = s[tid] - v;  // exclusive over partials
}

__global__ void k_scanC(int* rowoff, const int* __restrict__ partial, int n, int E) {
    int gid = blockIdx.x * blockDim.x + threadIdx.x;
    if (gid < n) rowoff[gid] += partial[gid >> 8];
    if (gid == 0) rowoff[n] = E;
}

// ---------------- CSR fill: colsrc sorted by dst ----------------
__global__ void k_fill(const int* __restrict__ edge, int E,
                       const int* __restrict__ rowoff, int* fill, int* colsrc) {
    int e = blockIdx.x * blockDim.x + threadIdx.x;
    if (e < E) {
        int dst = edge[E + e];
        int pos = rowoff[dst] + atomicAdd(&fill[dst], 1);
        colsrc[pos] = edge[e];
    }
}

// ---------------- h = x @ W  (fp32, 64-row x 128-col tiles, BK=32) ----------------
#define BM 64
#define BK 32
__global__ __launch_bounds__(256) void k_gemm(const float* __restrict__ x,
                                              const float* __restrict__ W,
                                              float* __restrict__ h) {
    __shared__ float Xs[BM][BK + 4];
    __shared__ float Ws[BK][128];
    int tid = threadIdx.x;
    int tx = tid & 15;
    int ty = tid >> 4;
    long r0 = (long)blockIdx.x * BM;

    float acc[4][8];
#pragma unroll
    for (int j = 0; j < 4; ++j)
#pragma unroll
        for (int c = 0; c < 8; ++c) acc[j][c] = 0.0f;

    for (int k0 = 0; k0 < 128; k0 += BK) {
#pragma unroll
        for (int it = 0; it < 2; ++it) {
            int i = tid + it * 256;
            int row = i >> 3;
            int kq = i & 7;
            float4 v = *(const float4*)&x[(r0 + row) * 128 + k0 + kq * 4];
            *(float4*)&Xs[row][kq * 4] = v;
        }
#pragma unroll
        for (int it = 0; it < 4; ++it) {
            int i = tid + it * 256;
            int kk = i >> 5;
            int cq = i & 31;
            *(float4*)&Ws[kk][cq * 4] = *(const float4*)&W[(k0 + kk) * 128 + cq * 4];
        }
        __syncthreads();

#pragma unroll
        for (int k = 0; k < BK; k += 4) {
            float4 xf[4];
#pragma unroll
            for (int j = 0; j < 4; ++j) xf[j] = *(const float4*)&Xs[ty * 4 + j][k];
#pragma unroll
            for (int kk = 0; kk < 4; ++kk) {
                float4 wa = *(const float4*)&Ws[k + kk][tx * 4];
                float4 wb = *(const float4*)&Ws[k + kk][tx * 4 + 64];
#pragma unroll
                for (int j = 0; j < 4; ++j) {
                    float xs = ((const float*)&xf[j])[kk];
                    acc[j][0] += xs * wa.x;
                    acc[j][1] += xs * wa.y;
                    acc[j][2] += xs * wa.z;
                    acc[j][3] += xs * wa.w;
                    acc[j][4] += xs * wb.x;
                    acc[j][5] += xs * wb.y;
                    acc[j][6] += xs * wb.z;
                    acc[j][7] += xs * wb.w;
                }
            }
        }
        __syncthreads();
    }
#pragma unroll
    for (int j = 0; j < 4; ++j) {
        long r = r0 + ty * 4 + j;
        float4 va = {acc[j][0], acc[j][1], acc[j][2], acc[j][3]};
        float4 vb = {acc[j][4], acc[j][5], acc[j][6], acc[j][7]};
        *(float4*)&h[r * 128 + tx * 4] = va;
        *(float4*)&h[r * 128 + tx * 4 + 64] = vb;
    }
}

// ---------------- aggregation + lrelu + pool: one block per graph ----------------
// 8 waves/block, each wave handles 16 nodes (stride 8), edge loop 4-deep pipelined,
// LDS reduction across waves -> direct pooled store (no atomics, no init needed).
#define AW 8     // waves per block
#define NPW 16   // nodes per wave (AW*NPW = 128 = nodes per graph)
__global__ __launch_bounds__(512) void k_aggr(const float* __restrict__ h,
                                              const int* __restrict__ colsrc,
                                              const int* __restrict__ rowoff,
                                              const float* __restrict__ dinv,
                                              const float* __restrict__ bias,
                                              float* __restrict__ pooled) {
    __shared__ float red[AW][128];
    int wave = threadIdx.x >> 6;
    int lane = threadIdx.x & 63;
    int g = blockIdx.x;

    float2 bv = ((const float2*)bias)[lane];
    float accx = 0.0f, accy = 0.0f;

    int v = g * 128 + wave;
    // prologue: load node 0's params
    int sc = rowoff[v];
    int ec = rowoff[v + 1];
    float dv = dinv[v];
    float2 self = ((const float2*)&h[(size_t)v * 128])[lane];

    for (int t = 0; t < NPW; ++t) {
        // issue next node's loads early (hidden under this node's edge loop)
        int vn = v + AW;
        int sn = 0, en = 0;
        float dvn = 0.0f;
        float2 selfn = {0.0f, 0.0f};
        if (t + 1 < NPW) {
            sn = rowoff[vn];
            en = rowoff[vn + 1];
            dvn = dinv[vn];
            selfn = ((const float2*)&h[(size_t)vn * 128])[lane];
        }

        float ax = self.x * dv * dv;
        float ay = self.y * dv * dv;
        int m = ec - sc;
        int full = m & ~3;
        for (int i = 0; i < full; i += 4) {
            int s0 = colsrc[sc + i];
            int s1 = colsrc[sc + i + 1];
            int s2 = colsrc[sc + i + 2];
            int s3 = colsrc[sc + i + 3];
            float w0 = dinv[s0] * dv;
            float w1 = dinv[s1] * dv;
            float w2 = dinv[s2] * dv;
            float w3 = dinv[s3] * dv;
            float2 h0 = ((const float2*)&h[(size_t)s0 * 128])[lane];
            float2 h1 = ((const float2*)&h[(size_t)s1 * 128])[lane];
            float2 h2 = ((const float2*)&h[(size_t)s2 * 128])[lane];
            float2 h3 = ((const float2*)&h[(size_t)s3 * 128])[lane];
            ax += h0.x * w0; ay += h0.y * w0;
            ax += h1.x * w1; ay += h1.y * w1;
            ax += h2.x * w2; ay += h2.y * w2;
            ax += h3.x * w3; ay += h3.y * w3;
        }
        for (int i = full; i < m; ++i) {
            int s0 = colsrc[sc + i];
            float w0 = dinv[s0] * dv;
            float2 h0 = ((const float2*)&h[(size_t)s0 * 128])[lane];
            ax += h0.x * w0; ay += h0.y * w0;
        }
        accx += lrelu(ax + bv.x);
        accy += lrelu(ay + bv.y);

        v = vn; sc = sn; ec = en; dv = dvn; self = selfn;
    }

    red[wave][lane * 2]     = accx;
    red[wave][lane * 2 + 1] = accy;
    __syncthreads();
    if (wave == 0) {
        float sx = 0.0f, sy = 0.0f;
#pragma unroll
        for (int w = 0; w < AW; ++w) {
            sx += red[w][lane * 2];
            sy += red[w][lane * 2 + 1];
        }
        pooled[(size_t)g * 128 + lane * 2]     = sx * (1.0f / 128.0f);
        pooled[(size_t)g * 128 + lane * 2 + 1] = sy * (1.0f / 128.0f);
    }
}

// ---------------- fused MLPs: 4 graph-rows per block ----------------
#define RB 4
__global__ __launch_bounds__(256) void k_mlp(const float* __restrict__ pooled,
                                             const float* __restrict__ w1a, const float* __restrict__ b1a,
                                             const float* __restrict__ w1b, const float* __restrict__ b1b,
                                             const float* __restrict__ w2a, const float* __restrict__ b2a,
                                             const float* __restrict__ w2b, const float* __restrict__ b2b,
                                             float* __restrict__ out, int B) {
    __shared__ float row[RB][128];
    __shared__ float hid[2][RB][256];
    int tid = threadIdx.x;
    int g0 = blockIdx.x * RB;

    for (int i = tid; i < RB * 128; i += 256)
        row[i >> 7][i & 127] = pooled[(size_t)g0 * 128 + i];
    __syncthreads();

    float a1[RB], a2[RB];
#pragma unroll
    for (int r = 0; r < RB; ++r) { a1[r] = 0.0f; a2[r] = 0.0f; }
    for (int k = 0; k < 128; ++k) {
        float wv1 = w1a[k * 256 + tid];
        float wv2 = w2a[k * 256 + tid];
#pragma unroll
        for (int r = 0; r < RB; ++r) {
            float xv = row[r][k];
            a1[r] += xv * wv1;
            a2[r] += xv * wv2;
        }
    }
    float bb1 = b1a[tid], bb2 = b2a[tid];
#pragma unroll
    for (int r = 0; r < RB; ++r) {
        hid[0][r][tid] = lrelu(a1[r] + bb1);
        hid[1][r][tid] = lrelu(a2[r] + bb2);
    }
    __syncthreads();

    int p = tid >> 7;
    int i = tid & 127;
    const float* wb = p ? w2b : w1b;
    const float* bvp = p ? b2b : b1b;
    float o[RB];
#pragma unroll
    for (int r = 0; r < RB; ++r) o[r] = 0.0f;
    for (int k = 0; k < 256; ++k) {
        float wv = wb[k * 128 + i];
#pragma unroll
        for (int r = 0; r < RB; ++r) o[r] += hid[p][r][k] * wv;
    }
    float bias = bvp[i];
#pragma unroll
    for (int r = 0; r < RB; ++r)
        out[(size_t)p * B * 128 + (size_t)(g0 + r) * 128 + i] = o[r] + bias;
}

extern "C" void kernel_launch(void* const* d_in, const int* in_sizes, int n_in,
                              void* d_out, int out_size, void* d_ws, size_t ws_size,
                              hipStream_t stream) {
    const float* x    = (const float*)d_in[0];
    const int*   edge = (const int*)d_in[1];
    const float* W    = (const float*)d_in[2];
    const float* b    = (const float*)d_in[3];
    const float* w1a  = (const float*)d_in[4];
    const float* b1a  = (const float*)d_in[5];
    const float* w1b  = (const float*)d_in[6];
    const float* b1b  = (const float*)d_in[7];
    const float* w2a  = (const float*)d_in[8];
    const float* b2a  = (const float*)d_in[9];
    const float* w2b  = (const float*)d_in[10];
    const float* b2b  = (const float*)d_in[11];

    int n = in_sizes[0] / 128;      // 131072 nodes
    int E = in_sizes[1] / 2;        // 2097152 edges
    int B = n / 128;                // 1024 graphs

    // workspace layout
    char* ws = (char*)d_ws;
    size_t off = 0;
    auto alloc = [&](size_t bytes) -> void* {
        void* p = ws + off;
        off = (off + bytes + 255) & ~(size_t)255;
        return p;
    };
    float* h      = (float*)alloc((size_t)n * 128 * 4);
    int*   cnt    = (int*)alloc((size_t)n * 4);
    int*   fill   = (int*)alloc((size_t)n * 4);
    int*   rowoff = (int*)alloc((size_t)(n + 1) * 4);
    float* dinv   = (float*)alloc((size_t)n * 4);
    int*   colsrc = (int*)alloc((size_t)E * 4);
    float* pooled = (float*)alloc((size_t)B * 128 * 4);
    int*   partial= (int*)alloc(2048 * 4);
    (void)ws_size; (void)n_in; (void)out_size;

    int nblk = (n + 255) / 256;          // 512
    int eblk = (E + 255) / 256;          // 8192
    int P    = (n + 255) / 256;          // 512

    hipMemsetAsync(cnt,  0, (size_t)n * 4, stream);
    hipMemsetAsync(fill, 0, (size_t)n * 4, stream);
    hipLaunchKernelGGL(k_count, dim3(eblk), dim3(256), 0, stream, edge, E, cnt);
    hipLaunchKernelGGL(k_scanA, dim3(nblk), dim3(256), 0, stream, cnt, rowoff, partial, dinv, n);
    hipLaunchKernelGGL(k_scanB, dim3(1),    dim3(P),   0, stream, partial, P);
    hipLaunchKernelGGL(k_scanC, dim3(nblk), dim3(256), 0, stream, rowoff, partial, n, E);
    hipLaunchKernelGGL(k_fill,  dim3(eblk), dim3(256), 0, stream, edge, E, rowoff, fill, colsrc);
    hipLaunchKernelGGL(k_gemm,  dim3(n / BM), dim3(256), 0, stream, x, W, h);
    hipLaunchKernelGGL(k_aggr,  dim3(B), dim3(512), 0, stream, h, colsrc, rowoff, dinv, b, pooled);
    hipLaunchKernelGGL(k_mlp,   dim3(B / RB), dim3(256), 0, stream,
                       pooled, w1a, b1a, w1b, b1b, w2a, b2a, w2b, b2b, (float*)d_out, B);
}

// Round 3
// 429.740 us; speedup vs baseline: 1.2727x; 1.0836x over previous
//
#include <hip/hip_runtime.h>

#define NEG_SLOPE 0.01f

static __device__ __forceinline__ float lrelu(float v) {
    return v >= 0.0f ? v : NEG_SLOPE * v;
}

// bf16 pack/unpack (RNE)
static __device__ __forceinline__ unsigned pack_bf16(float a, float b) {
    unsigned ua = __float_as_uint(a);
    unsigned ub = __float_as_uint(b);
    ua = (ua + 0x7FFFu + ((ua >> 16) & 1u)) >> 16;
    ub = (ub + 0x7FFFu + ((ub >> 16) & 1u)) >> 16;
    return ua | (ub << 16);
}
static __device__ __forceinline__ float bflo(unsigned u) { return __uint_as_float(u << 16); }
static __device__ __forceinline__ float bfhi(unsigned u) { return __uint_as_float(u & 0xFFFF0000u); }

// ---------------- degree histogram over dst ----------------
__global__ void k_count(const int* __restrict__ edge, int E, int* cnt) {
    int e = blockIdx.x * blockDim.x + threadIdx.x;
    if (e < E) atomicAdd(&cnt[edge[E + e]], 1);
}

// ---------------- 3-kernel exclusive scan (N = 131072 = 512*256), fused dinv ----------------
__global__ void k_scanA(const int* __restrict__ cnt, int* rowoff, int* partial,
                        float* dinv, int n) {
    __shared__ int s[256];
    int tid = threadIdx.x;
    int gid = blockIdx.x * 256 + tid;
    int v = (gid < n) ? cnt[gid] : 0;
    if (gid < n) dinv[gid] = rsqrtf((float)(v + 1));   // self loop included
    s[tid] = v;
    __syncthreads();
    for (int off = 1; off < 256; off <<= 1) {
        int t = (tid >= off) ? s[tid - off] : 0;
        __syncthreads();
        s[tid] += t;
        __syncthreads();
    }
    if (gid < n) rowoff[gid] = s[tid] - v;   // exclusive within chunk
    if (tid == 255) partial[blockIdx.x] = s[tid];
}

__global__ void k_scanB(int* partial, int P) {
    __shared__ int s[1024];
    int tid = threadIdx.x;
    int v = (tid < P) ? partial[tid] : 0;
    s[tid] = v;
    __syncthreads();
    for (int off = 1; off < P; off <<= 1) {
        int t = (tid >= off) ? s[tid - off] : 0;
        __syncthreads();
        s[tid] += t;
        __syncthreads();
    }
    if (tid < P) partial[tid] = s[tid] - v;  // exclusive over partials
}

__global__ void k_scanC(int* rowoff, int* fillpos, const int* __restrict__ partial, int n, int E) {
    int gid = blockIdx.x * blockDim.x + threadIdx.x;
    if (gid < n) {
        int r = rowoff[gid] + partial[gid >> 8];
        rowoff[gid] = r;
        fillpos[gid] = r;
    }
    if (gid == 0) rowoff[n] = E;
}

// ---------------- CSR fill: colsrc sorted by dst (rowptr-copy trick) ----------------
__global__ void k_fill(const int* __restrict__ edge, int E,
                       int* fillpos, int* colsrc) {
    int e = blockIdx.x * blockDim.x + threadIdx.x;
    if (e < E) {
        int dst = edge[E + e];
        int pos = atomicAdd(&fillpos[dst], 1);
        colsrc[pos] = edge[e];
    }
}

// ---------------- h = x @ W  (fp32 compute, bf16 output) ----------------
#define BM 64
#define BK 32
__global__ __launch_bounds__(256) void k_gemm(const float* __restrict__ x,
                                              const float* __restrict__ W,
                                              unsigned* __restrict__ h2) {
    __shared__ float Xs[BM][BK + 4];
    __shared__ float Ws[BK][128];
    int tid = threadIdx.x;
    int tx = tid & 15;
    int ty = tid >> 4;
    long r0 = (long)blockIdx.x * BM;

    float acc[4][8];
#pragma unroll
    for (int j = 0; j < 4; ++j)
#pragma unroll
        for (int c = 0; c < 8; ++c) acc[j][c] = 0.0f;

    for (int k0 = 0; k0 < 128; k0 += BK) {
#pragma unroll
        for (int it = 0; it < 2; ++it) {
            int i = tid + it * 256;
            int row = i >> 3;
            int kq = i & 7;
            float4 v = *(const float4*)&x[(r0 + row) * 128 + k0 + kq * 4];
            *(float4*)&Xs[row][kq * 4] = v;
        }
#pragma unroll
        for (int it = 0; it < 4; ++it) {
            int i = tid + it * 256;
            int kk = i >> 5;
            int cq = i & 31;
            *(float4*)&Ws[kk][cq * 4] = *(const float4*)&W[(k0 + kk) * 128 + cq * 4];
        }
        __syncthreads();

#pragma unroll
        for (int k = 0; k < BK; k += 4) {
            float4 xf[4];
#pragma unroll
            for (int j = 0; j < 4; ++j) xf[j] = *(const float4*)&Xs[ty * 4 + j][k];
#pragma unroll
            for (int kk = 0; kk < 4; ++kk) {
                float4 wa = *(const float4*)&Ws[k + kk][tx * 4];
                float4 wb = *(const float4*)&Ws[k + kk][tx * 4 + 64];
#pragma unroll
                for (int j = 0; j < 4; ++j) {
                    float xs = ((const float*)&xf[j])[kk];
                    acc[j][0] += xs * wa.x;
                    acc[j][1] += xs * wa.y;
                    acc[j][2] += xs * wa.z;
                    acc[j][3] += xs * wa.w;
                    acc[j][4] += xs * wb.x;
                    acc[j][5] += xs * wb.y;
                    acc[j][6] += xs * wb.z;
                    acc[j][7] += xs * wb.w;
                }
            }
        }
        __syncthreads();
    }
#pragma unroll
    for (int j = 0; j < 4; ++j) {
        long r = r0 + ty * 4 + j;
        uint2 pa, pb;
        pa.x = pack_bf16(acc[j][0], acc[j][1]);
        pa.y = pack_bf16(acc[j][2], acc[j][3]);
        pb.x = pack_bf16(acc[j][4], acc[j][5]);
        pb.y = pack_bf16(acc[j][6], acc[j][7]);
        *(uint2*)&h2[r * 64 + tx * 2] = pa;
        *(uint2*)&h2[r * 64 + 32 + tx * 2] = pb;
    }
}

// ---------------- aggregation + lrelu + pool: one block per graph ----------------
// Per node: lanes gather ALL edge (src,dinv) in parallel, broadcast via shfl ->
// h-row gathers have no dependent chain; 4-deep unrolled. bf16 h rows (256B).
#define AW 8     // waves per block
#define NPW 16   // nodes per wave
__global__ __launch_bounds__(512) void k_aggr(const unsigned* __restrict__ h2,
                                              const int* __restrict__ colsrc,
                                              const int* __restrict__ rowoff,
                                              const float* __restrict__ dinv,
                                              const float* __restrict__ bias,
                                              float* __restrict__ pooled) {
    __shared__ float red[AW][128];
    int wave = threadIdx.x >> 6;
    int lane = threadIdx.x & 63;
    int g = blockIdx.x;

    float2 bv = ((const float2*)bias)[lane];
    float accx = 0.0f, accy = 0.0f;

    int v = g * 128 + wave;
    int sc = rowoff[v];
    int ec = rowoff[v + 1];
    float dv = dinv[v];
    unsigned self = h2[(size_t)v * 64 + lane];

    for (int t = 0; t < NPW; ++t) {
        // prefetch next node's params under this node's edge loop
        int vn = v + AW;
        int sn = 0, en = 0;
        float dvn = 0.0f;
        unsigned selfn = 0;
        if (t + 1 < NPW) {
            sn = rowoff[vn];
            en = rowoff[vn + 1];
            dvn = dinv[vn];
            selfn = h2[(size_t)vn * 64 + lane];
        }

        float dv2 = dv * dv;
        float ax = bflo(self) * dv2;
        float ay = bfhi(self) * dv2;
        int m = ec - sc;
        for (int base = 0; base < m; base += 64) {
            int mb = min(64, m - base);
            int se = 0;
            float we = 0.0f;
            if (lane < mb) {
                se = colsrc[sc + base + lane];
                we = dinv[se] * dv;
            }
            int full = mb & ~3;
            for (int j = 0; j < full; j += 4) {
                int s0 = __shfl(se, j);
                int s1 = __shfl(se, j + 1);
                int s2 = __shfl(se, j + 2);
                int s3 = __shfl(se, j + 3);
                float w0 = __shfl(we, j);
                float w1 = __shfl(we, j + 1);
                float w2 = __shfl(we, j + 2);
                float w3 = __shfl(we, j + 3);
                unsigned u0 = h2[(size_t)s0 * 64 + lane];
                unsigned u1 = h2[(size_t)s1 * 64 + lane];
                unsigned u2 = h2[(size_t)s2 * 64 + lane];
                unsigned u3 = h2[(size_t)s3 * 64 + lane];
                ax += bflo(u0) * w0; ay += bfhi(u0) * w0;
                ax += bflo(u1) * w1; ay += bfhi(u1) * w1;
                ax += bflo(u2) * w2; ay += bfhi(u2) * w2;
                ax += bflo(u3) * w3; ay += bfhi(u3) * w3;
            }
            for (int j = full; j < mb; ++j) {
                int s0 = __shfl(se, j);
                float w0 = __shfl(we, j);
                unsigned u0 = h2[(size_t)s0 * 64 + lane];
                ax += bflo(u0) * w0; ay += bfhi(u0) * w0;
            }
        }
        accx += lrelu(ax + bv.x);
        accy += lrelu(ay + bv.y);

        v = vn; sc = sn; ec = en; dv = dvn; self = selfn;
    }

    red[wave][lane * 2]     = accx;
    red[wave][lane * 2 + 1] = accy;
    __syncthreads();
    if (wave == 0) {
        float sx = 0.0f, sy = 0.0f;
#pragma unroll
        for (int w = 0; w < AW; ++w) {
            sx += red[w][lane * 2];
            sy += red[w][lane * 2 + 1];
        }
        pooled[(size_t)g * 128 + lane * 2]     = sx * (1.0f / 128.0f);
        pooled[(size_t)g * 128 + lane * 2 + 1] = sy * (1.0f / 128.0f);
    }
}

// ---------------- fused MLPs: 4 graph-rows per block ----------------
#define RB 4
__global__ __launch_bounds__(256) void k_mlp(const float* __restrict__ pooled,
                                             const float* __restrict__ w1a, const float* __restrict__ b1a,
                                             const float* __restrict__ w1b, const float* __restrict__ b1b,
                                             const float* __restrict__ w2a, const float* __restrict__ b2a,
                                             const float* __restrict__ w2b, const float* __restrict__ b2b,
                                             float* __restrict__ out, int B) {
    __shared__ float row[RB][128];
    __shared__ float hid[2][RB][256];
    int tid = threadIdx.x;
    int g0 = blockIdx.x * RB;

    for (int i = tid; i < RB * 128; i += 256)
        row[i >> 7][i & 127] = pooled[(size_t)g0 * 128 + i];
    __syncthreads();

    float a1[RB], a2[RB];
#pragma unroll
    for (int r = 0; r < RB; ++r) { a1[r] = 0.0f; a2[r] = 0.0f; }
    for (int k = 0; k < 128; ++k) {
        float wv1 = w1a[k * 256 + tid];
        float wv2 = w2a[k * 256 + tid];
#pragma unroll
        for (int r = 0; r < RB; ++r) {
            float xv = row[r][k];
            a1[r] += xv * wv1;
            a2[r] += xv * wv2;
        }
    }
    float bb1 = b1a[tid], bb2 = b2a[tid];
#pragma unroll
    for (int r = 0; r < RB; ++r) {
        hid[0][r][tid] = lrelu(a1[r] + bb1);
        hid[1][r][tid] = lrelu(a2[r] + bb2);
    }
    __syncthreads();

    int p = tid >> 7;
    int i = tid & 127;
    const float* wb = p ? w2b : w1b;
    const float* bvp = p ? b2b : b1b;
    float o[RB];
#pragma unroll
    for (int r = 0; r < RB; ++r) o[r] = 0.0f;
    for (int k = 0; k < 256; ++k) {
        float wv = wb[k * 128 + i];
#pragma unroll
        for (int r = 0; r < RB; ++r) o[r] += hid[p][r][k] * wv;
    }
    float bias = bvp[i];
#pragma unroll
    for (int r = 0; r < RB; ++r)
        out[(size_t)p * B * 128 + (size_t)(g0 + r) * 128 + i] = o[r] + bias;
}

extern "C" void kernel_launch(void* const* d_in, const int* in_sizes, int n_in,
                              void* d_out, int out_size, void* d_ws, size_t ws_size,
                              hipStream_t stream) {
    const float* x    = (const float*)d_in[0];
    const int*   edge = (const int*)d_in[1];
    const float* W    = (const float*)d_in[2];
    const float* b    = (const float*)d_in[3];
    const float* w1a  = (const float*)d_in[4];
    const float* b1a  = (const float*)d_in[5];
    const float* w1b  = (const float*)d_in[6];
    const float* b1b  = (const float*)d_in[7];
    const float* w2a  = (const float*)d_in[8];
    const float* b2a  = (const float*)d_in[9];
    const float* w2b  = (const float*)d_in[10];
    const float* b2b  = (const float*)d_in[11];

    int n = in_sizes[0] / 128;      // 131072 nodes
    int E = in_sizes[1] / 2;        // 2097152 edges
    int B = n / 128;                // 1024 graphs

    char* ws = (char*)d_ws;
    size_t off = 0;
    auto alloc = [&](size_t bytes) -> void* {
        void* p = ws + off;
        off = (off + bytes + 255) & ~(size_t)255;
        return p;
    };
    unsigned* h2     = (unsigned*)alloc((size_t)n * 64 * 4);   // bf16x2 rows
    int*      cnt    = (int*)alloc((size_t)n * 4);
    int*      fillpos= (int*)alloc((size_t)n * 4);
    int*      rowoff = (int*)alloc((size_t)(n + 1) * 4);
    float*    dinv   = (float*)alloc((size_t)n * 4);
    int*      colsrc = (int*)alloc((size_t)E * 4);
    float*    pooled = (float*)alloc((size_t)B * 128 * 4);
    int*      partial= (int*)alloc(2048 * 4);
    (void)ws_size; (void)n_in; (void)out_size;

    int nblk = (n + 255) / 256;          // 512
    int eblk = (E + 255) / 256;          // 8192
    int P    = (n + 255) / 256;          // 512

    hipMemsetAsync(cnt, 0, (size_t)n * 4, stream);
    hipLaunchKernelGGL(k_count, dim3(eblk), dim3(256), 0, stream, edge, E, cnt);
    hipLaunchKernelGGL(k_scanA, dim3(nblk), dim3(256), 0, stream, cnt, rowoff, partial, dinv, n);
    hipLaunchKernelGGL(k_scanB, dim3(1),    dim3(P),   0, stream, partial, P);
    hipLaunchKernelGGL(k_scanC, dim3(nblk), dim3(256), 0, stream, rowoff, fillpos, partial, n, E);
    hipLaunchKernelGGL(k_fill,  dim3(eblk), dim3(256), 0, stream, edge, E, fillpos, colsrc);
    hipLaunchKernelGGL(k_gemm,  dim3(n / BM), dim3(256), 0, stream, x, W, h2);
    hipLaunchKernelGGL(k_aggr,  dim3(B), dim3(512), 0, stream, h2, colsrc, rowoff, dinv, b, pooled);
    hipLaunchKernelGGL(k_mlp,   dim3(B / RB), dim3(256), 0, stream,
                       pooled, w1a, b1a, w1b, b1b, w2a, b2a, w2b, b2b, (float*)d_out, B);
}

// Round 4
// 414.898 us; speedup vs baseline: 1.3183x; 1.0358x over previous
//
#include <hip/hip_runtime.h>

#define NEG_SLOPE 0.01f

static __device__ __forceinline__ float lrelu(float v) {
    return v >= 0.0f ? v : NEG_SLOPE * v;
}

// bf16 pack/unpack (RNE)
static __device__ __forceinline__ unsigned pack_bf16(float a, float b) {
    unsigned ua = __float_as_uint(a);
    unsigned ub = __float_as_uint(b);
    ua = (ua + 0x7FFFu + ((ua >> 16) & 1u)) >> 16;
    ub = (ub + 0x7FFFu + ((ub >> 16) & 1u)) >> 16;
    return ua | (ub << 16);
}
static __device__ __forceinline__ float bflo(unsigned u) { return __uint_as_float(u << 16); }
static __device__ __forceinline__ float bfhi(unsigned u) { return __uint_as_float(u & 0xFFFF0000u); }

#define EPT 8   // edges per thread in count/fill (8 independent atomics in flight)

// ---------------- degree histogram over dst (8-way ILP) ----------------
__global__ void k_count(const int* __restrict__ edge, int E, int* cnt) {
    int t = blockIdx.x * blockDim.x + threadIdx.x;
    int base = t * EPT;
    if (base + EPT <= E) {
        int4 a = *(const int4*)&edge[E + base];
        int4 b = *(const int4*)&edge[E + base + 4];
        atomicAdd(&cnt[a.x], 1);
        atomicAdd(&cnt[a.y], 1);
        atomicAdd(&cnt[a.z], 1);
        atomicAdd(&cnt[a.w], 1);
        atomicAdd(&cnt[b.x], 1);
        atomicAdd(&cnt[b.y], 1);
        atomicAdd(&cnt[b.z], 1);
        atomicAdd(&cnt[b.w], 1);
    } else {
        for (int i = base; i < E; ++i) atomicAdd(&cnt[edge[E + i]], 1);
    }
}

// ---------------- 3-kernel exclusive scan (N = 131072 = 512*256), fused dinv ----------------
__global__ void k_scanA(const int* __restrict__ cnt, int* rowoff, int* partial,
                        float* dinv, int n) {
    __shared__ int s[256];
    int tid = threadIdx.x;
    int gid = blockIdx.x * 256 + tid;
    int v = (gid < n) ? cnt[gid] : 0;
    if (gid < n) dinv[gid] = rsqrtf((float)(v + 1));   // self loop included
    s[tid] = v;
    __syncthreads();
    for (int off = 1; off < 256; off <<= 1) {
        int t = (tid >= off) ? s[tid - off] : 0;
        __syncthreads();
        s[tid] += t;
        __syncthreads();
    }
    if (gid < n) rowoff[gid] = s[tid] - v;
    if (tid == 255) partial[blockIdx.x] = s[tid];
}

__global__ void k_scanB(int* partial, int P) {
    __shared__ int s[1024];
    int tid = threadIdx.x;
    int v = (tid < P) ? partial[tid] : 0;
    s[tid] = v;
    __syncthreads();
    for (int off = 1; off < P; off <<= 1) {
        int t = (tid >= off) ? s[tid - off] : 0;
        __syncthreads();
        s[tid] += t;
        __syncthreads();
    }
    if (tid < P) partial[tid] = s[tid] - v;
}

__global__ void k_scanC(int* rowoff, int* fillpos, const int* __restrict__ partial, int n, int E) {
    int gid = blockIdx.x * blockDim.x + threadIdx.x;
    if (gid < n) {
        int r = rowoff[gid] + partial[gid >> 8];
        rowoff[gid] = r;
        fillpos[gid] = r;
    }
    if (gid == 0) rowoff[n] = E;
}

// ---------------- CSR fill (8-way ILP: 8 independent atomic round-trips) ----------------
__global__ void k_fill(const int* __restrict__ edge, int E,
                       int* fillpos, int* colsrc) {
    int t = blockIdx.x * blockDim.x + threadIdx.x;
    int base = t * EPT;
    if (base + EPT <= E) {
        int4 sa = *(const int4*)&edge[base];
        int4 sb = *(const int4*)&edge[base + 4];
        int4 da = *(const int4*)&edge[E + base];
        int4 db = *(const int4*)&edge[E + base + 4];
        int p0 = atomicAdd(&fillpos[da.x], 1);
        int p1 = atomicAdd(&fillpos[da.y], 1);
        int p2 = atomicAdd(&fillpos[da.z], 1);
        int p3 = atomicAdd(&fillpos[da.w], 1);
        int p4 = atomicAdd(&fillpos[db.x], 1);
        int p5 = atomicAdd(&fillpos[db.y], 1);
        int p6 = atomicAdd(&fillpos[db.z], 1);
        int p7 = atomicAdd(&fillpos[db.w], 1);
        colsrc[p0] = sa.x;
        colsrc[p1] = sa.y;
        colsrc[p2] = sa.z;
        colsrc[p3] = sa.w;
        colsrc[p4] = sb.x;
        colsrc[p5] = sb.y;
        colsrc[p6] = sb.z;
        colsrc[p7] = sb.w;
    } else {
        for (int i = base; i < E; ++i) {
            int dst = edge[E + i];
            int pos = atomicAdd(&fillpos[dst], 1);
            colsrc[pos] = edge[i];
        }
    }
}

// ---------------- h = x @ W  (fp32 compute, bf16 output) ----------------
#define BM 64
#define BK 32
__global__ __launch_bounds__(256) void k_gemm(const float* __restrict__ x,
                                              const float* __restrict__ W,
                                              unsigned* __restrict__ h2) {
    __shared__ float Xs[BM][BK + 4];
    __shared__ float Ws[BK][128];
    int tid = threadIdx.x;
    int tx = tid & 15;
    int ty = tid >> 4;
    long r0 = (long)blockIdx.x * BM;

    float acc[4][8];
#pragma unroll
    for (int j = 0; j < 4; ++j)
#pragma unroll
        for (int c = 0; c < 8; ++c) acc[j][c] = 0.0f;

    for (int k0 = 0; k0 < 128; k0 += BK) {
#pragma unroll
        for (int it = 0; it < 2; ++it) {
            int i = tid + it * 256;
            int row = i >> 3;
            int kq = i & 7;
            float4 v = *(const float4*)&x[(r0 + row) * 128 + k0 + kq * 4];
            *(float4*)&Xs[row][kq * 4] = v;
        }
#pragma unroll
        for (int it = 0; it < 4; ++it) {
            int i = tid + it * 256;
            int kk = i >> 5;
            int cq = i & 31;
            *(float4*)&Ws[kk][cq * 4] = *(const float4*)&W[(k0 + kk) * 128 + cq * 4];
        }
        __syncthreads();

#pragma unroll
        for (int k = 0; k < BK; k += 4) {
            float4 xf[4];
#pragma unroll
            for (int j = 0; j < 4; ++j) xf[j] = *(const float4*)&Xs[ty * 4 + j][k];
#pragma unroll
            for (int kk = 0; kk < 4; ++kk) {
                float4 wa = *(const float4*)&Ws[k + kk][tx * 4];
                float4 wb = *(const float4*)&Ws[k + kk][tx * 4 + 64];
#pragma unroll
                for (int j = 0; j < 4; ++j) {
                    float xs = ((const float*)&xf[j])[kk];
                    acc[j][0] += xs * wa.x;
                    acc[j][1] += xs * wa.y;
                    acc[j][2] += xs * wa.z;
                    acc[j][3] += xs * wa.w;
                    acc[j][4] += xs * wb.x;
                    acc[j][5] += xs * wb.y;
                    acc[j][6] += xs * wb.z;
                    acc[j][7] += xs * wb.w;
                }
            }
        }
        __syncthreads();
    }
#pragma unroll
    for (int j = 0; j < 4; ++j) {
        long r = r0 + ty * 4 + j;
        uint2 pa, pb;
        pa.x = pack_bf16(acc[j][0], acc[j][1]);
        pa.y = pack_bf16(acc[j][2], acc[j][3]);
        pb.x = pack_bf16(acc[j][4], acc[j][5]);
        pb.y = pack_bf16(acc[j][6], acc[j][7]);
        *(uint2*)&h2[r * 64 + tx * 2] = pa;
        *(uint2*)&h2[r * 64 + 32 + tx * 2] = pb;
    }
}

// ---------------- aggregation + lrelu + pool: one block per graph ----------------
#define AW 8     // waves per block
#define NPW 16   // nodes per wave
__global__ __launch_bounds__(512) void k_aggr(const unsigned* __restrict__ h2,
                                              const int* __restrict__ colsrc,
                                              const int* __restrict__ rowoff,
                                              const float* __restrict__ dinv,
                                              const float* __restrict__ bias,
                                              float* __restrict__ pooled) {
    __shared__ float red[AW][128];
    int wave = threadIdx.x >> 6;
    int lane = threadIdx.x & 63;
    int g = blockIdx.x;

    float2 bv = ((const float2*)bias)[lane];
    float accx = 0.0f, accy = 0.0f;

    int v = g * 128 + wave;
    int sc = rowoff[v];
    int ec = rowoff[v + 1];
    float dv = dinv[v];
    unsigned self = h2[(size_t)v * 64 + lane];

    for (int t = 0; t < NPW; ++t) {
        int vn = v + AW;
        int sn = 0, en = 0;
        float dvn = 0.0f;
        unsigned selfn = 0;
        if (t + 1 < NPW) {
            sn = rowoff[vn];
            en = rowoff[vn + 1];
            dvn = dinv[vn];
            selfn = h2[(size_t)vn * 64 + lane];
        }

        float dv2 = dv * dv;
        float ax = bflo(self) * dv2;
        float ay = bfhi(self) * dv2;
        int m = ec - sc;
        for (int base = 0; base < m; base += 64) {
            int mb = min(64, m - base);
            int se = 0;
            float we = 0.0f;
            if (lane < mb) {
                se = colsrc[sc + base + lane];
                we = dinv[se] * dv;
            }
            int full = mb & ~3;
            for (int j = 0; j < full; j += 4) {
                int s0 = __shfl(se, j);
                int s1 = __shfl(se, j + 1);
                int s2 = __shfl(se, j + 2);
                int s3 = __shfl(se, j + 3);
                float w0 = __shfl(we, j);
                float w1 = __shfl(we, j + 1);
                float w2 = __shfl(we, j + 2);
                float w3 = __shfl(we, j + 3);
                unsigned u0 = h2[(size_t)s0 * 64 + lane];
                unsigned u1 = h2[(size_t)s1 * 64 + lane];
                unsigned u2 = h2[(size_t)s2 * 64 + lane];
                unsigned u3 = h2[(size_t)s3 * 64 + lane];
                ax += bflo(u0) * w0; ay += bfhi(u0) * w0;
                ax += bflo(u1) * w1; ay += bfhi(u1) * w1;
                ax += bflo(u2) * w2; ay += bfhi(u2) * w2;
                ax += bflo(u3) * w3; ay += bfhi(u3) * w3;
            }
            for (int j = full; j < mb; ++j) {
                int s0 = __shfl(se, j);
                float w0 = __shfl(we, j);
                unsigned u0 = h2[(size_t)s0 * 64 + lane];
                ax += bflo(u0) * w0; ay += bfhi(u0) * w0;
            }
        }
        accx += lrelu(ax + bv.x);
        accy += lrelu(ay + bv.y);

        v = vn; sc = sn; ec = en; dv = dvn; self = selfn;
    }

    red[wave][lane * 2]     = accx;
    red[wave][lane * 2 + 1] = accy;
    __syncthreads();
    if (wave == 0) {
        float sx = 0.0f, sy = 0.0f;
#pragma unroll
        for (int w = 0; w < AW; ++w) {
            sx += red[w][lane * 2];
            sy += red[w][lane * 2 + 1];
        }
        pooled[(size_t)g * 128 + lane * 2]     = sx * (1.0f / 128.0f);
        pooled[(size_t)g * 128 + lane * 2 + 1] = sy * (1.0f / 128.0f);
    }
}

// ---------------- fused MLPs: 4 graph-rows per block ----------------
#define RB 4
__global__ __launch_bounds__(256) void k_mlp(const float* __restrict__ pooled,
                                             const float* __restrict__ w1a, const float* __restrict__ b1a,
                                             const float* __restrict__ w1b, const float* __restrict__ b1b,
                                             const float* __restrict__ w2a, const float* __restrict__ b2a,
                                             const float* __restrict__ w2b, const float* __restrict__ b2b,
                                             float* __restrict__ out, int B) {
    __shared__ float row[RB][128];
    __shared__ float hid[2][RB][256];
    int tid = threadIdx.x;
    int g0 = blockIdx.x * RB;

    for (int i = tid; i < RB * 128; i += 256)
        row[i >> 7][i & 127] = pooled[(size_t)g0 * 128 + i];
    __syncthreads();

    float a1[RB], a2[RB];
#pragma unroll
    for (int r = 0; r < RB; ++r) { a1[r] = 0.0f; a2[r] = 0.0f; }
    for (int k = 0; k < 128; ++k) {
        float wv1 = w1a[k * 256 + tid];
        float wv2 = w2a[k * 256 + tid];
#pragma unroll
        for (int r = 0; r < RB; ++r) {
            float xv = row[r][k];
            a1[r] += xv * wv1;
            a2[r] += xv * wv2;
        }
    }
    float bb1 = b1a[tid], bb2 = b2a[tid];
#pragma unroll
    for (int r = 0; r < RB; ++r) {
        hid[0][r][tid] = lrelu(a1[r] + bb1);
        hid[1][r][tid] = lrelu(a2[r] + bb2);
    }
    __syncthreads();

    int p = tid >> 7;
    int i = tid & 127;
    const float* wb = p ? w2b : w1b;
    const float* bvp = p ? b2b : b1b;
    float o[RB];
#pragma unroll
    for (int r = 0; r < RB; ++r) o[r] = 0.0f;
    for (int k = 0; k < 256; ++k) {
        float wv = wb[k * 128 + i];
#pragma unroll
        for (int r = 0; r < RB; ++r) o[r] += hid[p][r][k] * wv;
    }
    float bias = bvp[i];
#pragma unroll
    for (int r = 0; r < RB; ++r)
        out[(size_t)p * B * 128 + (size_t)(g0 + r) * 128 + i] = o[r] + bias;
}

extern "C" void kernel_launch(void* const* d_in, const int* in_sizes, int n_in,
                              void* d_out, int out_size, void* d_ws, size_t ws_size,
                              hipStream_t stream) {
    const float* x    = (const float*)d_in[0];
    const int*   edge = (const int*)d_in[1];
    const float* W    = (const float*)d_in[2];
    const float* b    = (const float*)d_in[3];
    const float* w1a  = (const float*)d_in[4];
    const float* b1a  = (const float*)d_in[5];
    const float* w1b  = (const float*)d_in[6];
    const float* b1b  = (const float*)d_in[7];
    const float* w2a  = (const float*)d_in[8];
    const float* b2a  = (const float*)d_in[9];
    const float* w2b  = (const float*)d_in[10];
    const float* b2b  = (const float*)d_in[11];

    int n = in_sizes[0] / 128;      // 131072 nodes
    int E = in_sizes[1] / 2;        // 2097152 edges
    int B = n / 128;                // 1024 graphs

    char* ws = (char*)d_ws;
    size_t off = 0;
    auto alloc = [&](size_t bytes) -> void* {
        void* p = ws + off;
        off = (off + bytes + 255) & ~(size_t)255;
        return p;
    };
    unsigned* h2     = (unsigned*)alloc((size_t)n * 64 * 4);   // bf16x2 rows
    int*      cnt    = (int*)alloc((size_t)n * 4);
    int*      fillpos= (int*)alloc((size_t)n * 4);
    int*      rowoff = (int*)alloc((size_t)(n + 1) * 4);
    float*    dinv   = (float*)alloc((size_t)n * 4);
    int*      colsrc = (int*)alloc((size_t)E * 4);
    float*    pooled = (float*)alloc((size_t)B * 128 * 4);
    int*      partial= (int*)alloc(2048 * 4);
    (void)ws_size; (void)n_in; (void)out_size;

    int nblk  = (n + 255) / 256;               // 512
    int eblk8 = (E + 256 * EPT - 1) / (256 * EPT);  // 1024
    int P     = (n + 255) / 256;               // 512

    hipMemsetAsync(cnt, 0, (size_t)n * 4, stream);
    hipLaunchKernelGGL(k_count, dim3(eblk8), dim3(256), 0, stream, edge, E, cnt);
    hipLaunchKernelGGL(k_scanA, dim3(nblk), dim3(256), 0, stream, cnt, rowoff, partial, dinv, n);
    hipLaunchKernelGGL(k_scanB, dim3(1),    dim3(P),   0, stream, partial, P);
    hipLaunchKernelGGL(k_scanC, dim3(nblk), dim3(256), 0, stream, rowoff, fillpos, partial, n, E);
    hipLaunchKernelGGL(k_fill,  dim3(eblk8), dim3(256), 0, stream, edge, E, fillpos, colsrc);
    hipLaunchKernelGGL(k_gemm,  dim3(n / BM), dim3(256), 0, stream, x, W, h2);
    hipLaunchKernelGGL(k_aggr,  dim3(B), dim3(512), 0, stream, h2, colsrc, rowoff, dinv, b, pooled);
    hipLaunchKernelGGL(k_mlp,   dim3(B / RB), dim3(256), 0, stream,
                       pooled, w1a, b1a, w1b, b1b, w2a, b2a, w2b, b2b, (float*)d_out, B);
}